// Round 1
// baseline (25.031 us; speedup 1.0000x reference)
//
#include <hip/hip_runtime.h>
#include <hip/hip_bf16.h>
#include <cmath>

// RoiPoolingConv: per-ROI crop + legacy-TF bilinear resize.
// img [1,H,W,C] f32, rois [1,R,4] i32 (x,y,w,h), out [1,R,P,P,C] f32.
// One block per output pixel (r,i,j); 256 threads x float2 covers C=512.

__global__ __launch_bounds__(256) void roi_pool_kernel(
    const float* __restrict__ img, const int* __restrict__ rois,
    float* __restrict__ out, int P, int H, int W, int C) {
  const int b = blockIdx.x;
  const int pp = P * P;
  const int r = b / pp;
  const int ij = b - r * pp;
  const int i = ij / P;
  const int j = ij - i * P;

  const int x = rois[r * 4 + 0];
  const int y = rois[r * 4 + 1];
  const int w = rois[r * 4 + 2];
  const int h = rois[r * 4 + 3];

  const float Pf = (float)P;
  // Match reference fp32 semantics exactly:
  // sy = y + i * (h / P); sx = x + j * (w / P)
  const float sy = (float)y + (float)i * ((float)h / Pf);
  const float sx = (float)x + (float)j * ((float)w / Pf);
  const float fy = floorf(sy);
  const float fx = floorf(sx);
  int y0 = (int)fy;
  int x0 = (int)fx;
  int y1 = min(y0 + 1, y + h - 1);   // from UNclipped y0
  int x1 = min(x0 + 1, x + w - 1);
  y0 = min(max(y0, 0), H - 1);
  y1 = min(max(y1, 0), H - 1);
  x0 = min(max(x0, 0), W - 1);
  x1 = min(max(x1, 0), W - 1);
  const float wy = sy - fy;          // from UNclipped floor
  const float wx = sx - fx;
  const float omwx = 1.0f - wx;
  const float omwy = 1.0f - wy;

  const float* __restrict__ p00 = img + ((size_t)y0 * W + x0) * C;
  const float* __restrict__ p01 = img + ((size_t)y0 * W + x1) * C;
  const float* __restrict__ p10 = img + ((size_t)y1 * W + x0) * C;
  const float* __restrict__ p11 = img + ((size_t)y1 * W + x1) * C;
  float* __restrict__ po = out + (size_t)b * C;

  for (int c = threadIdx.x * 2; c < C; c += blockDim.x * 2) {
    const float2 v00 = *reinterpret_cast<const float2*>(p00 + c);
    const float2 v01 = *reinterpret_cast<const float2*>(p01 + c);
    const float2 v10 = *reinterpret_cast<const float2*>(p10 + c);
    const float2 v11 = *reinterpret_cast<const float2*>(p11 + c);
    float2 o;
    {
      const float top = v00.x * omwx + v01.x * wx;
      const float bot = v10.x * omwx + v11.x * wx;
      o.x = top * omwy + bot * wy;
    }
    {
      const float top = v00.y * omwx + v01.y * wx;
      const float bot = v10.y * omwx + v11.y * wx;
      o.y = top * omwy + bot * wy;
    }
    *reinterpret_cast<float2*>(po + c) = o;
  }
}

extern "C" void kernel_launch(void* const* d_in, const int* in_sizes, int n_in,
                              void* d_out, int out_size, void* d_ws, size_t ws_size,
                              hipStream_t stream) {
  const float* img = (const float*)d_in[0];
  const int* rois = (const int*)d_in[1];
  float* out = (float*)d_out;

  const int H = 200, W = 200, C = 512;
  const int R = in_sizes[1] / 4;                    // 300
  const int pp = out_size / (R * C);                // P*P = 49
  int P = 1;
  while ((P + 1) * (P + 1) <= pp) ++P;              // isqrt -> 7

  const int blocks = R * pp;                        // 14,700
  roi_pool_kernel<<<blocks, 256, 0, stream>>>(img, rois, out, P, H, W, C);
}

// Round 2
// 24.893 us; speedup vs baseline: 1.0055x; 1.0055x over previous
//
#include <hip/hip_runtime.h>
#include <hip/hip_bf16.h>
#include <cmath>

// RoiPoolingConv: per-ROI crop + legacy-TF bilinear resize.
// img [1,H,W,C] f32, rois [1,R,4] i32 (x,y,w,h), out [1,R,P,P,C] f32.
// One block per (roi, i) output row: P waves, wave j owns pixel (i,j),
// lane owns 8 channels via 2x float4 (8 independent 16B loads in flight).

__global__ __launch_bounds__(448) void roi_pool_kernel(
    const float* __restrict__ img, const int* __restrict__ rois,
    float* __restrict__ out, int P, int H, int W, int C) {
  const int b = blockIdx.x;          // r*P + i
  const int r = b / P;
  const int i = b - r * P;
  const int j = threadIdx.x >> 6;    // wave index = output column
  const int lane = threadIdx.x & 63;

  const int x = rois[r * 4 + 0];
  const int y = rois[r * 4 + 1];
  const int w = rois[r * 4 + 2];
  const int h = rois[r * 4 + 3];

  const float Pf = (float)P;
  // Match reference fp32 semantics exactly:
  // sy = y + i * (h / P); sx = x + j * (w / P)
  const float sy = (float)y + (float)i * ((float)h / Pf);
  const float sx = (float)x + (float)j * ((float)w / Pf);
  const float fy = floorf(sy);
  const float fx = floorf(sx);
  int y0 = (int)fy;
  int x0 = (int)fx;
  int y1 = min(y0 + 1, y + h - 1);   // from UNclipped y0
  int x1 = min(x0 + 1, x + w - 1);
  y0 = min(max(y0, 0), H - 1);
  y1 = min(max(y1, 0), H - 1);
  x0 = min(max(x0, 0), W - 1);
  x1 = min(max(x1, 0), W - 1);
  const float wy = sy - fy;          // from UNclipped floor
  const float wx = sx - fx;
  const float omwx = 1.0f - wx;
  const float omwy = 1.0f - wy;

  const float* __restrict__ p00 = img + ((size_t)y0 * W + x0) * C;
  const float* __restrict__ p01 = img + ((size_t)y0 * W + x1) * C;
  const float* __restrict__ p10 = img + ((size_t)y1 * W + x0) * C;
  const float* __restrict__ p11 = img + ((size_t)y1 * W + x1) * C;
  float* __restrict__ po = out + ((size_t)b * P + j) * C;

  // lane covers channels [lane*8, lane*8+8): two float4 per source pixel.
  for (int c = lane * 8; c < C; c += 64 * 8) {
    const float4 a00 = *reinterpret_cast<const float4*>(p00 + c);
    const float4 b00 = *reinterpret_cast<const float4*>(p00 + c + 4);
    const float4 a01 = *reinterpret_cast<const float4*>(p01 + c);
    const float4 b01 = *reinterpret_cast<const float4*>(p01 + c + 4);
    const float4 a10 = *reinterpret_cast<const float4*>(p10 + c);
    const float4 b10 = *reinterpret_cast<const float4*>(p10 + c + 4);
    const float4 a11 = *reinterpret_cast<const float4*>(p11 + c);
    const float4 b11 = *reinterpret_cast<const float4*>(p11 + c + 4);

    float4 oa, ob;
#define LERP1(F, v00_, v01_, v10_, v11_)                      \
    {                                                          \
      const float top = v00_.F * omwx + v01_.F * wx;           \
      const float bot = v10_.F * omwx + v11_.F * wx;           \
      oa.F = top * omwy + bot * wy;                            \
    }
#define LERP2(F, v00_, v01_, v10_, v11_)                      \
    {                                                          \
      const float top = v00_.F * omwx + v01_.F * wx;           \
      const float bot = v10_.F * omwx + v11_.F * wx;           \
      ob.F = top * omwy + bot * wy;                            \
    }
    LERP1(x, a00, a01, a10, a11)
    LERP1(y, a00, a01, a10, a11)
    LERP1(z, a00, a01, a10, a11)
    LERP1(w, a00, a01, a10, a11)
    LERP2(x, b00, b01, b10, b11)
    LERP2(y, b00, b01, b10, b11)
    LERP2(z, b00, b01, b10, b11)
    LERP2(w, b00, b01, b10, b11)
#undef LERP1
#undef LERP2
    *reinterpret_cast<float4*>(po + c) = oa;
    *reinterpret_cast<float4*>(po + c + 4) = ob;
  }
}

extern "C" void kernel_launch(void* const* d_in, const int* in_sizes, int n_in,
                              void* d_out, int out_size, void* d_ws, size_t ws_size,
                              hipStream_t stream) {
  const float* img = (const float*)d_in[0];
  const int* rois = (const int*)d_in[1];
  float* out = (float*)d_out;

  const int H = 200, W = 200, C = 512;
  const int R = in_sizes[1] / 4;                    // 300
  const int pp = out_size / (R * C);                // P*P = 49
  int P = 1;
  while ((P + 1) * (P + 1) <= pp) ++P;              // isqrt -> 7

  const int blocks = R * P;                         // 2100 (r,i) rows
  roi_pool_kernel<<<blocks, P * 64, 0, stream>>>(img, rois, out, P, H, W, C);
}